// Round 3
// baseline (335.874 us; speedup 1.0000x reference)
//
#include <hip/hip_runtime.h>
#include <hip/hip_bf16.h>
#include <math.h>

#define DIM 768
#define NH 12
#define HD 64
#define BATCH 16
#define SEQ 1024
#define M_TOTAL (BATCH * SEQ)   // 16384
#define MATE ((size_t)M_TOTAL * DIM)  // elements per activation plane

typedef unsigned short ushort_t;
typedef __attribute__((ext_vector_type(8))) short short8;
typedef __attribute__((ext_vector_type(4))) float floatx4;

__device__ __constant__ float kScale = 0.03608439182435161f; // 1/sqrt(768)

__device__ inline ushort_t f2b(float x) {
    __hip_bfloat16 h = __float2bfloat16(x);
    return __builtin_bit_cast(ushort_t, h);
}
__device__ inline float b2f_u32(unsigned int bits16) {
    union { unsigned int i; float f; } c;
    c.i = bits16 << 16;
    return c.f;
}
__device__ inline float b2f(ushort_t u) { return b2f_u32((unsigned int)u); }

// async global->LDS, 16 B per lane; LDS dest is wave-uniform base + lane*16
__device__ __forceinline__ void gl2lds16(const ushort_t* g, ushort_t* l) {
    __builtin_amdgcn_global_load_lds(
        (__attribute__((address_space(1))) void*)g,
        (__attribute__((address_space(3))) void*)l, 16, 0, 0);
}

#define BAR() do { \
    __builtin_amdgcn_sched_barrier(0); \
    __builtin_amdgcn_s_barrier(); \
    __builtin_amdgcn_sched_barrier(0); \
} while (0)

// ---------------------------------------------------------------------------
// fp32 -> bf16 plane
// ---------------------------------------------------------------------------
__global__ __launch_bounds__(256) void cvt_bf16_kernel(
    const float* __restrict__ X, ushort_t* __restrict__ Y, int n4)
{
    int i = blockIdx.x * 256 + threadIdx.x;
    if (i >= n4) return;
    float4 v = ((const float4*)X)[i];
    ushort4 o;
    o.x = f2b(v.x); o.y = f2b(v.y); o.z = f2b(v.z); o.w = f2b(v.w);
    ((ushort4*)Y)[i] = o;
}

// ---------------------------------------------------------------------------
// All 4 weights: W[k][n] fp32 -> transposed bf16 plane Wt[n][k].
// ---------------------------------------------------------------------------
__global__ __launch_bounds__(256) void transpose4_kernel(
    const float* __restrict__ W0, const float* __restrict__ W1,
    const float* __restrict__ W2, const float* __restrict__ W3,
    ushort_t* __restrict__ qkv_t, ushort_t* __restrict__ o_t)
{
    const int z = blockIdx.z;
    const float* W = (z == 0) ? W0 : (z == 1) ? W1 : (z == 2) ? W2 : W3;
    ushort_t* hi = (z < 3) ? qkv_t + (size_t)z * DIM * DIM : o_t;

    __shared__ float t[64][65];
    const int k0 = blockIdx.x * 64, n0 = blockIdx.y * 64;
    const int lr = threadIdx.x >> 2, lc = (threadIdx.x & 3) * 16;
    #pragma unroll
    for (int j = 0; j < 4; ++j) {
        float4 v = *(const float4*)&W[(size_t)(k0 + lr) * DIM + n0 + lc + j * 4];
        t[lr][lc + j * 4 + 0] = v.x;
        t[lr][lc + j * 4 + 1] = v.y;
        t[lr][lc + j * 4 + 2] = v.z;
        t[lr][lc + j * 4 + 3] = v.w;
    }
    __syncthreads();
    #pragma unroll
    for (int j = 0; j < 16; ++j)
        hi[(size_t)(n0 + lr) * DIM + k0 + lc + j] = f2b(t[lc + j][lr]);
}

__global__ __launch_bounds__(256) void bias_concat_kernel(
    const float* __restrict__ bq, const float* __restrict__ bk,
    const float* __restrict__ bv, float* __restrict__ ball)
{
    int i = blockIdx.x * 256 + threadIdx.x;
    if (i >= 3 * DIM) return;
    float v = (i < DIM) ? bq[i] : (i < 2 * DIM ? bk[i - DIM] : bv[i - 2 * DIM]);
    ball[i] = v;
}

// ---------------------------------------------------------------------------
// bf16 MFMA GEMM, 256x256 tile, BK=64, 8 waves (512 thr), 8-phase-style
// deep pipeline (m201 lineage):
//   - LDS 128 KB: 2 buffers x (A 256x64 + B 256x64) bf16.
//   - 12 K-tiles; 4 phases per K-tile. Phase p: ds_read A row-pair subtile
//     (4 b128; + all 8 B b128 at p0, held in regs), stage ONE half-tile
//     (2 global_load_lds), barrier, lgkmcnt(0)+sched_barrier, setprio(1),
//     16 MFMA -> acc[2p..2p+1][0..3], setprio(0), barrier.
//   - counted vmcnt: stage order per iter t = A0(t+1),A1(t+1),B0(t+2),
//     B1(t+2); ONE vmcnt(4) at end of iter leaves exactly B(t+2) in flight
//     (FIFO forces A(t+1)+B(t+1) landed). Never drains mid-loop.
//   - XOR slot swizzle (involution): 128B row, 16B slot s stored at
//     s^(row&7); gl2lds keeps linear LDS dest + inverse-swizzled SOURCE;
//     ds_read_b128 conflict-free.
//   - XCD swizzle: bid&7 = xcd, rows fast (8 M-blocks/XCD, A strip 3 MB
//     L2-resident across col sweeps).
// EPI 0: Q pre-scaled; q/k -> [B,H,N,HD] bf16; V -> [B,H,HD,N]. (9 col blk)
// EPI 1: fp32 [M,768] row-major.                               (3 col blk)
// ---------------------------------------------------------------------------
template <int EPI>
__global__ __launch_bounds__(512, 2) void mfma_gemm(
    const ushort_t* __restrict__ A, const ushort_t* __restrict__ Bhi,
    const float* __restrict__ bias, void* __restrict__ Cout)
{
    constexpr int NT = 12;                 // K tiles (768/64)
    __shared__ ushort_t smem[2 * 32768];   // 128 KB

    const int bid = blockIdx.x;
    const int xcd = bid & 7;
    const int o = bid >> 3;
    const int row0 = (xcd * 8 + (o & 7)) * 256;   // M blocks: 64 = 8 XCD x 8
    const int col0 = (o >> 3) * 256;

    const int tid = threadIdx.x;
    const int lane = tid & 63;
    const int wv = tid >> 6;           // 0..7
    const int wm = (wv >> 2) * 128;    // 2 M-warps
    const int wn = (wv & 3) * 64;      // 4 N-warps
    const int m16 = lane & 15;
    const int quad = lane >> 4;

    // staging: half-tile = 128 rows x 64 cols = 1024 x 16B slots.
    // thread's slots q = (wv*2+j)*64 + lane; row = q>>3, phys slot = q&7
    // holds logical slot (q&7)^(row&7)  (inverse-swizzled source).
    size_t srcA[2], srcB[2];
    int ldsoff[2];
    #pragma unroll
    for (int j = 0; j < 2; ++j) {
        const int q = (wv * 2 + j) * 64 + lane;
        const int r = q >> 3;
        const int s = (q & 7) ^ (r & 7);
        srcA[j] = (size_t)(row0 + r) * DIM + s * 8;
        srcB[j] = (size_t)(col0 + r) * DIM + s * 8;
        ldsoff[j] = (wv * 2 + j) * 512;    // wave-uniform dest (ushorts)
    }

    auto stageA = [&](int half, int kt, ushort_t* buf) {
        const size_t hb = (size_t)half * 128 * DIM + (size_t)kt * 64;
        ushort_t* d = buf + half * 8192;
        gl2lds16(A + hb + srcA[0], d + ldsoff[0]);
        gl2lds16(A + hb + srcA[1], d + ldsoff[1]);
    };
    auto stageB = [&](int half, int kt, ushort_t* buf) {
        const size_t hb = (size_t)half * 128 * DIM + (size_t)kt * 64;
        ushort_t* d = buf + 16384 + half * 8192;
        gl2lds16(Bhi + hb + srcB[0], d + ldsoff[0]);
        gl2lds16(Bhi + hb + srcB[1], d + ldsoff[1]);
    };

    floatx4 acc[8][4];
    #pragma unroll
    for (int i = 0; i < 8; ++i)
        #pragma unroll
        for (int j = 0; j < 4; ++j)
            acc[i][j] = (floatx4){0.f, 0.f, 0.f, 0.f};

    // prologue: tile0 (A+B) + B(1); 12 loads; allow B(1)'s 4 in flight
    stageA(0, 0, smem); stageA(1, 0, smem);
    stageB(0, 0, smem); stageB(1, 0, smem);
    stageB(0, 1, smem + 32768); stageB(1, 1, smem + 32768);
    asm volatile("s_waitcnt vmcnt(4)" ::: "memory");
    BAR();

    for (int t = 0; t < NT; ++t) {
        ushort_t* bc = smem + (t & 1) * 32768;
        ushort_t* bn = smem + ((t & 1) ^ 1) * 32768;
        const ushort_t* a = bc;
        const ushort_t* b = bc + 16384;
        short8 bf[4][2];
        #pragma unroll
        for (int p = 0; p < 4; ++p) {
            short8 af[2][2];
            if (p == 0) {
                #pragma unroll
                for (int n = 0; n < 4; ++n)
                    #pragma unroll
                    for (int s = 0; s < 2; ++s) {
                        const int r = wn + n * 16 + m16;
                        bf[n][s] = *(const short8*)&b[r * 64 + ((s * 4 + quad) ^ (r & 7)) * 8];
                    }
            }
            #pragma unroll
            for (int i = 0; i < 2; ++i)
                #pragma unroll
                for (int s = 0; s < 2; ++s) {
                    const int r = wm + (p * 2 + i) * 16 + m16;
                    af[i][s] = *(const short8*)&a[r * 64 + ((s * 4 + quad) ^ (r & 7)) * 8];
                }
            if (p == 0 && t + 1 < NT) stageA(0, t + 1, bn);
            if (p == 1) {
                if (t + 1 < NT) stageA(1, t + 1, bn);
                if (t + 2 < NT) stageB(0, t + 2, bc);
            }
            if (p == 2 && t + 2 < NT) stageB(1, t + 2, bc);
            BAR();
            asm volatile("s_waitcnt lgkmcnt(0)" ::: "memory");
            __builtin_amdgcn_sched_barrier(0);
            __builtin_amdgcn_s_setprio(1);
            #pragma unroll
            for (int i = 0; i < 2; ++i)
                #pragma unroll
                for (int n = 0; n < 4; ++n)
                    #pragma unroll
                    for (int s = 0; s < 2; ++s)
                        acc[p * 2 + i][n] = __builtin_amdgcn_mfma_f32_16x16x32_bf16(
                            af[i][s], bf[n][s], acc[p * 2 + i][n], 0, 0, 0);
            __builtin_amdgcn_s_setprio(0);
            if (p == 3) {
                if (t < NT - 2) asm volatile("s_waitcnt vmcnt(4)" ::: "memory");
                else            asm volatile("s_waitcnt vmcnt(0)" ::: "memory");
            }
            BAR();
        }
    }

    if (EPI == 0) {
        const int proj = col0 / DIM;      // 256 | 768 -> uniform per block
        const int rem0 = col0 % DIM;
        const float sc = (proj == 0) ? kScale : 1.0f;   // pre-scale Q
        ushort_t* C = (ushort_t*)Cout + (size_t)proj * MATE;
        #pragma unroll
        for (int n = 0; n < 4; ++n) {
            const int coff = wn + n * 16 + m16;
            const int cc = rem0 + coff;
            const int h = cc >> 6, dd = cc & 63;
            const float bs2 = bias[col0 + coff];
            #pragma unroll
            for (int m = 0; m < 8; ++m)
                #pragma unroll
                for (int r = 0; r < 4; ++r) {
                    const int mm = row0 + wm + m * 16 + quad * 4 + r;
                    const int bb = mm >> 10, nn = mm & 1023;
                    if (proj < 2) {
                        C[(((size_t)(bb * NH + h) * SEQ + nn) << 6) + dd] =
                            f2b((acc[m][n][r] + bs2) * sc);
                    } else {
                        C[((((size_t)(bb * NH + h) << 6) + dd) << 10) + nn] =
                            f2b(acc[m][n][r] + bs2);
                    }
                }
        }
    } else {
        float* C = (float*)Cout;
        #pragma unroll
        for (int n = 0; n < 4; ++n) {
            const int coff = wn + n * 16 + m16;
            const float bs2 = bias[col0 + coff];
            #pragma unroll
            for (int m = 0; m < 8; ++m)
                #pragma unroll
                for (int r = 0; r < 4; ++r) {
                    const int mm = row0 + wm + m * 16 + quad * 4 + r;
                    C[(size_t)mm * DIM + col0 + coff] = acc[m][n][r] + bs2;
                }
        }
    }
}

// ---------------------------------------------------------------------------
// MFMA flash attention (unchanged this round).
// ---------------------------------------------------------------------------
#define APK 72   // LDS row pitch (bf16): 144 B
__global__ __launch_bounds__(256) void attn_kernel(
    const ushort_t* __restrict__ Q, const ushort_t* __restrict__ K,
    const ushort_t* __restrict__ Vt, ushort_t* __restrict__ Aout)
{
    __shared__ ushort_t Ks[64 * APK];
    __shared__ ushort_t Vs[64 * APK];
    __shared__ ushort_t Ps[128 * APK];   // P tile; reused for O at the end

    const int bid = blockIdx.x;          // 1536 blocks
    const int xcd = bid & 7;
    const int o = bid >> 3;              // 0..191
    const int bh = xcd * 24 + (o >> 3);  // 24 heads per XCD
    const int q0 = (o & 7) * 128;        // q-tiles fast -> K/V L2 reuse

    const int tid = threadIdx.x;
    const int lane = tid & 63;
    const int wave = tid >> 6;
    const int wq = wave * 32;
    const int m16 = lane & 15;
    const int quad = lane >> 4;
    const size_t base  = (size_t)bh * SEQ * HD;   // Q,K: [N][HD]
    const size_t baseT = (size_t)bh * HD * SEQ;   // Vt:  [HD][N]

    const int sr = tid >> 2;            // staging row 0..63
    const int sc = (tid & 3) * 16;      // staging chunk (bf16)

    // Q A-fragments: 2 q-frags x 2 k-chunks, held in regs whole kernel
    short8 qf[2][2];
    #pragma unroll
    for (int f = 0; f < 2; ++f)
        #pragma unroll
        for (int kc = 0; kc < 2; ++kc)
            qf[f][kc] = *(const short8*)&Q[base +
                (size_t)(q0 + wq + f * 16 + m16) * HD + kc * 32 + quad * 8];

    floatx4 oacc[2][4];
    float lacc[2][4];
    #pragma unroll
    for (int f = 0; f < 2; ++f) {
        #pragma unroll
        for (int dt = 0; dt < 4; ++dt) oacc[f][dt] = (floatx4){0.f, 0.f, 0.f, 0.f};
        #pragma unroll
        for (int r = 0; r < 4; ++r) lacc[f][r] = 0.0f;
    }

    // prefetch tile 0
    uint4 kv0 = *(const uint4*)&K[base + (size_t)sr * HD + sc];
    uint4 kv1 = *(const uint4*)&K[base + (size_t)sr * HD + sc + 8];
    uint4 vv0 = *(const uint4*)&Vt[baseT + (size_t)sr * SEQ + sc];
    uint4 vv1 = *(const uint4*)&Vt[baseT + (size_t)sr * SEQ + sc + 8];

    for (int kt = 0; kt < SEQ / 64; ++kt) {
        __syncthreads();   // all waves done reading prev Ks/Vs
        *(uint4*)&Ks[sr * APK + sc] = kv0;
        *(uint4*)&Ks[sr * APK + sc + 8] = kv1;
        *(uint4*)&Vs[sr * APK + sc] = vv0;
        *(uint4*)&Vs[sr * APK + sc + 8] = vv1;
        __syncthreads();
        if (kt + 1 < SEQ / 64) {   // prefetch next tile (overlaps compute)
            const int k1 = (kt + 1) * 64;
            kv0 = *(const uint4*)&K[base + (size_t)(k1 + sr) * HD + sc];
            kv1 = *(const uint4*)&K[base + (size_t)(k1 + sr) * HD + sc + 8];
            vv0 = *(const uint4*)&Vt[baseT + (size_t)sr * SEQ + k1 + sc];
            vv1 = *(const uint4*)&Vt[baseT + (size_t)sr * SEQ + k1 + sc + 8];
        }

        // S = Q K^T : K frags read once, reused for both q-frags
        short8 kf[2][4];
        #pragma unroll
        for (int kc = 0; kc < 2; ++kc)
            #pragma unroll
            for (int t = 0; t < 4; ++t)
                kf[kc][t] = *(const short8*)&Ks[(t * 16 + m16) * APK + kc * 32 + quad * 8];
        floatx4 sacc[2][4];
        #pragma unroll
        for (int f = 0; f < 2; ++f)
            #pragma unroll
            for (int t = 0; t < 4; ++t)
                sacc[f][t] = (floatx4){0.f, 0.f, 0.f, 0.f};
        #pragma unroll
        for (int kc = 0; kc < 2; ++kc)
            #pragma unroll
            for (int f = 0; f < 2; ++f)
                #pragma unroll
                for (int t = 0; t < 4; ++t)
                    sacc[f][t] = __builtin_amdgcn_mfma_f32_16x16x32_bf16(
                        qf[f][kc], kf[kc][t], sacc[f][t], 0, 0, 0);

        // max-free softmax: p = exp(s); per-lane partial row sums
        #pragma unroll
        for (int f = 0; f < 2; ++f)
            #pragma unroll
            for (int r = 0; r < 4; ++r) {
                float rs = 0.0f;
                #pragma unroll
                for (int t = 0; t < 4; ++t) {
                    ushort_t u = f2b(__expf(sacc[f][t][r]));
                    Ps[(wq + f * 16 + quad * 4 + r) * APK + t * 16 + m16] = u;
                    rs += b2f(u);   // sum ROUNDED p -> exact normalization
                }
                lacc[f][r] += rs;
            }

        // O += P V
        short8 vf[2][4];
        #pragma unroll
        for (int kc = 0; kc < 2; ++kc)
            #pragma unroll
            for (int dt = 0; dt < 4; ++dt)
                vf[kc][dt] = *(const short8*)&Vs[(dt * 16 + m16) * APK + kc * 32 + quad * 8];
        #pragma unroll
        for (int f = 0; f < 2; ++f) {
            #pragma unroll
            for (int kc = 0; kc < 2; ++kc) {
                short8 pf = *(const short8*)&Ps[(wq + f * 16 + m16) * APK + kc * 32 + quad * 8];
                #pragma unroll
                for (int dt = 0; dt < 4; ++dt)
                    oacc[f][dt] = __builtin_amdgcn_mfma_f32_16x16x32_bf16(
                        pf, vf[kc][dt], oacc[f][dt], 0, 0, 0);
            }
        }
    }

    // one cross-lane reduction for l, then normalize
    float inv[2][4];
    #pragma unroll
    for (int f = 0; f < 2; ++f)
        #pragma unroll
        for (int r = 0; r < 4; ++r) {
            float l = lacc[f][r];
            l += __shfl_xor(l, 1);
            l += __shfl_xor(l, 2);
            l += __shfl_xor(l, 4);
            l += __shfl_xor(l, 8);
            inv[f][r] = 1.0f / l;
        }

    // stage O (bf16) into Ps [q][d] (wave-private rows), then coalesced store
    #pragma unroll
    for (int f = 0; f < 2; ++f)
        #pragma unroll
        for (int dt = 0; dt < 4; ++dt)
            #pragma unroll
            for (int r = 0; r < 4; ++r)
                Ps[(wq + f * 16 + quad * 4 + r) * APK + dt * 16 + m16] =
                    f2b(oacc[f][dt][r] * inv[f][r]);
    __syncthreads();

    const int b = bh / NH, h = bh % NH;
    const int orow = tid >> 1;             // 0..127
    const int oc = (tid & 1) * 32;         // bf16 offset
    const size_t row = (size_t)b * SEQ + q0 + orow;
    #pragma unroll
    for (int j = 0; j < 4; ++j) {
        uint4 ov = *(const uint4*)&Ps[orow * APK + oc + j * 8];
        *(uint4*)&Aout[row * DIM + h * HD + oc + j * 8] = ov;
    }
}

extern "C" void kernel_launch(void* const* d_in, const int* in_sizes, int n_in,
                              void* d_out, int out_size, void* d_ws, size_t ws_size,
                              hipStream_t stream)
{
    const float* X  = (const float*)d_in[0];
    const float* Wq = (const float*)d_in[1];
    const float* bq = (const float*)d_in[2];
    const float* Wk = (const float*)d_in[3];
    const float* bk = (const float*)d_in[4];
    const float* Wv = (const float*)d_in[5];
    const float* bv = (const float*)d_in[6];
    const float* Wo = (const float*)d_in[7];
    const float* bo = (const float*)d_in[8];

    ushort_t* qkv  = (ushort_t*)d_ws;                 // q,k [B,H,N,HD]; v [B,H,HD,N]
    ushort_t* abuf = qkv + 3 * MATE;
    ushort_t* xbf  = abuf + MATE;
    ushort_t* wqkv_t = xbf + MATE;                    // 2304*768 bf16
    ushort_t* wo_t   = wqkv_t + (size_t)3 * DIM * DIM;
    float* ball = (float*)(wo_t + (size_t)DIM * DIM); // 2304 floats

    cvt_bf16_kernel<<<(int)(MATE / 4 + 255) / 256, 256, 0, stream>>>(X, xbf, (int)(MATE / 4));
    transpose4_kernel<<<dim3(DIM / 64, DIM / 64, 4), 256, 0, stream>>>(
        Wq, Wk, Wv, Wo, wqkv_t, wo_t);
    bias_concat_kernel<<<(3 * DIM + 255) / 256, 256, 0, stream>>>(bq, bk, bv, ball);

    // QKV projection: 64 row-blocks x 9 col-blocks, XCD-swizzled 1-D
    mfma_gemm<0><<<dim3(8 * 72), 512, 0, stream>>>(xbf, wqkv_t, ball, qkv);

    attn_kernel<<<dim3((SEQ / 128) * BATCH * NH), 256, 0, stream>>>(
        qkv, qkv + MATE, qkv + 2 * MATE, abuf);

    // out projection: 64 row-blocks x 3 col-blocks, XCD-swizzled 1-D
    mfma_gemm<1><<<dim3(8 * 24), 512, 0, stream>>>(abuf, wo_t, bo, d_out);
}